// Round 11
// baseline (511.123 us; speedup 1.0000x reference)
//
#include <hip/hip_runtime.h>
#include <math.h>

#define BB 4
#define DD 31

typedef _Float16 half8 __attribute__((ext_vector_type(8)));
typedef float f32x4 __attribute__((ext_vector_type(4)));

__device__ __forceinline__ int swz(int b) { return b ^ (((b >> 7) & 7) << 4); }
__device__ __forceinline__ half8 ldswz(const _Float16* lin, int byteoff) {
    return *(const half8*)((const char*)lin + swz(byteoff));
}
__device__ __forceinline__ void stswz(_Float16* lin, int byteoff, half8 v) {
    *(half8*)((char*)lin + swz(byteoff)) = v;
}
__device__ __forceinline__ float fast_tanh(float y) {
    float e = __expf(2.f * y);
    return 1.f - 2.f * __builtin_amdgcn_rcpf(e + 1.f);
}
__device__ __forceinline__ float fast_sigmoid(float y) {
    return __builtin_amdgcn_rcpf(1.f + __expf(-y));
}

// ---------------- prep kernels ----------------

__global__ void bnprep(const float* __restrict__ bn, int C, float* __restrict__ sh) {
    int c = threadIdx.x;
    if (c >= C) return;
    float g = bn[c], b = bn[C + c], m = bn[2 * C + c], v = bn[3 * C + c];
    sh[c] = b - m * (g * rsqrtf(v + 1e-5f));
}

// r5 layout: dst[ko][co][ki]; k = ko*32+ki = tap*CIN+ci, zero-pad k>=27*CIN
// tr=0: W = src[co][ci][tap]; tr=1 (deconv): W = src[ci][co][26-tap]. BN scale folded.
__global__ void wprepA(const float* __restrict__ src, const float* __restrict__ bn,
                       _Float16* __restrict__ dst, int CIN, int COUT, int KS, int tr) {
    int idx = blockIdx.x * 256 + threadIdx.x;
    int total = KS * 32 * COUT;
    if (idx >= total) return;
    int ki = idx % 32;
    int co = (idx / 32) % COUT;
    int ko = idx / (32 * COUT);
    int k = ko * 32 + ki;
    float v = 0.f;
    if (k < 27 * CIN) {
        int tap = k / CIN, ci = k % CIN;
        v = tr ? src[((size_t)ci * COUT + co) * 27 + (26 - tap)]
               : src[((size_t)co * CIN + ci) * 27 + tap];
        v *= bn[co] * rsqrtf(bn[3 * COUT + co] + 1e-5f);
    }
    dst[((size_t)ko * COUT + co) * 32 + ki] = (_Float16)v;
}

// fused layout (CS=1): dst[ko][n][c16][ki]; co = n*(COUT/2)+c16
__global__ void wprepC(const float* __restrict__ src, const float* __restrict__ bn,
                       _Float16* __restrict__ dst, int CIN, int COUT, int KS, int tr) {
    int idx = blockIdx.x * 256 + threadIdx.x;
    int total = KS * 1024;
    if (idx >= total) return;
    int ki = idx & 31;
    int c16 = (idx >> 5) & 15;
    int n = (idx >> 9) & 1;
    int ko = idx >> 10;
    int co = n * (COUT / 2) + c16;
    int k = ko * 32 + ki;
    float v = 0.f;
    if (k < 27 * CIN) {
        int tap = k / CIN, ci = k % CIN;
        v = tr ? src[((size_t)ci * COUT + co) * 27 + (26 - tap)]
               : src[((size_t)co * CIN + ci) * 27 + tap];
        v *= bn[co] * rsqrtf(bn[3 * COUT + co] + 1e-5f);
    }
    dst[idx] = (_Float16)v;
}

// collapsed upsample weights, r5 layout (unfused conv_up, L1):
// dst[par][ko][co][ki]; tap = (kd*2+ih)*2+iw (12 taps)
__global__ void wprep_upA(const float* __restrict__ src, const float* __restrict__ bn,
                          _Float16* __restrict__ dst, int CIN, int COUT) {
    const int KS = 12 * CIN / 32;
    int idx = blockIdx.x * 256 + threadIdx.x;
    int total = 4 * KS * 32 * COUT;
    if (idx >= total) return;
    int ki = idx % 32;
    int co = (idx / 32) % COUT;
    int ko = (idx / (32 * COUT)) % KS;
    int par = idx / (32 * COUT * KS);
    int k = ko * 32 + ki;
    int ci = k % CIN, tap = k / CIN;
    int kd = tap >> 2, ih = (tap >> 1) & 1, iw = tap & 1;
    int ph = par >> 1, pw = par & 1;
    const float c[2][2][3] = {{{1, 0, 0}, {0, 1, 1}}, {{1, 1, 0}, {0, 0, 1}}};
    float v = 0.f;
    for (int kh = 0; kh < 3; ++kh)
        for (int kw = 0; kw < 3; ++kw)
            v += c[ph][ih][kh] * c[pw][iw][kw] *
                 src[((size_t)co * CIN + ci) * 27 + kd * 9 + kh * 3 + kw];
    v *= bn[co] * rsqrtf(bn[3 * COUT + co] + 1e-5f);
    dst[(((size_t)par * KS + ko) * COUT + co) * 32 + ki] = (_Float16)v;
}

// collapsed upsample weights, fused layout (fconv_up1, L3): dst[par][ko][n][c16][ki]
__global__ void wprep_upB(const float* __restrict__ src, const float* __restrict__ bn,
                          _Float16* __restrict__ dst, int CIN, int COUT, int KS) {
    int idx = blockIdx.x * 256 + threadIdx.x;
    int total = 4 * KS * 1024;
    if (idx >= total) return;
    int ki = idx & 31;
    int c16 = (idx >> 5) & 15;
    int n = (idx >> 9) & 1;
    int ko = (idx >> 10) % KS;
    int par = idx / (KS * 1024);
    int co = n * (COUT / 2) + c16;
    int k = ko * 32 + ki;
    int ci = k % CIN, tap = k / CIN;
    int kd = tap >> 2, ih = (tap >> 1) & 1, iw = tap & 1;
    int ph = par >> 1, pw = par & 1;
    const float c[2][2][3] = {{{1, 0, 0}, {0, 1, 1}}, {{1, 1, 0}, {0, 0, 1}}};
    float v = 0.f;
    for (int kh = 0; kh < 3; ++kh)
        for (int kw = 0; kw < 3; ++kw)
            v += c[ph][ih][kh] * c[pw][iw][kw] *
                 src[((size_t)co * CIN + ci) * 27 + kd * 9 + kh * 3 + kw];
    v *= bn[co] * rsqrtf(bn[3 * COUT + co] + 1e-5f);
    dst[idx] = (_Float16)v;
}

// x [4][64][31][1024] f32 NCDHW -> xf [4*31][1024][64] f16 NDHWC
__global__ __launch_bounds__(256) void xconv(const float* __restrict__ src,
                                             _Float16* __restrict__ dst) {
    int idx = blockIdx.x * 256 + threadIdx.x;
    if (idx >= 4 * 31 * 1024 * 8) return;
    int cb = idx & 7;
    int pos = (idx >> 3) & 1023;
    int bd = idx >> 13;
    int d = bd % 31, b = bd / 31;
    half8 v;
#pragma unroll
    for (int j = 0; j < 8; ++j)
        v[j] = (_Float16)src[(((size_t)b * 64 + cb * 8 + j) * 31 + d) * 1024 + pos];
    *(half8*)(dst + ((size_t)bd * 1024 + pos) * 64 + cb * 8) = v;
}

// xs f32 [B][C][DD][HW] -> f16 [B*DD][HW][C]  (coalesced reads per channel,
// per-thread contiguous C*2-byte write)
template <int C, int HW>
__global__ __launch_bounds__(256) void xst(const float* __restrict__ src,
                                           _Float16* __restrict__ dst) {
    int hw = blockIdx.x * 256 + threadIdx.x;
    int bd = blockIdx.y;
    int d = bd % DD, b = bd / DD;
    _Float16 tmp[C];
#pragma unroll
    for (int c = 0; c < C; ++c)
        tmp[c] = (_Float16)src[((size_t)(b * C + c) * DD + d) * HW + hw];
#pragma unroll
    for (int c8 = 0; c8 < C / 8; ++c8)
        *(half8*)(dst + ((size_t)bd * HW + hw) * C + c8 * 8) = *(half8*)(tmp + c8 * 8);
}

// ---------------- UNFUSED collapsed upsample conv (layer 1) ----------------
template <int CIN, int COUT, int S, int MINW>
__global__ __launch_bounds__(256, MINW) void conv_up(
    const _Float16* __restrict__ inp,   // [B*DD][S/2][S/2][CIN] f16
    const _Float16* __restrict__ wqu,   // [4][KS][COUT][32] f16
    const float* __restrict__ bnsh,
    _Float16* __restrict__ gout) {      // [B*DD][S][S][COUT] f16

    constexpr int SIN = S / 2;
    constexpr int KS = 12 * CIN / 32;
    constexpr int NCB = COUT / 16;
    constexpr int NC8 = CIN / 8;
    constexpr int IH = 6, IW = 18;
    constexpr int PATCH = 3 * IH * IW;

    __shared__ __align__(16) _Float16 lin[PATCH * CIN];

    const int tid = threadIdx.x;
    const int lane = tid & 63;
    const int wv = tid >> 6;
    const int col = lane & 15;
    const int grp = lane >> 4;
    const int ph = wv >> 1, pw = wv & 1;

    const int bwp = blockIdx.x * 16;
    const int bhp = blockIdx.y * 4;
    const int bz = blockIdx.z;
    const int d = bz % DD;

    for (int idx = tid; idx < PATCH * NC8; idx += 256) {
        int c8 = idx % NC8;
        int pos = idx / NC8;
        int iwp = pos % IW, t = pos / IW;
        int ihp = t % IH, kd = t / IH;
        int dz = d + kd - 1, gh = bhp - 1 + ihp, gw = bwp - 1 + iwp;
        half8 v = {0, 0, 0, 0, 0, 0, 0, 0};
        if ((unsigned)dz < (unsigned)DD && (unsigned)gh < (unsigned)SIN &&
            (unsigned)gw < (unsigned)SIN)
            v = *(const half8*)(inp +
                (((size_t)(bz + kd - 1) * SIN + gh) * SIN + gw) * CIN + c8 * 8);
        *(half8*)((char*)lin + swz((pos * CIN + c8 * 8) * 2)) = v;
    }
    __syncthreads();

    f32x4 acc[4][NCB];
#pragma unroll
    for (int f = 0; f < 4; ++f)
#pragma unroll
        for (int n = 0; n < NCB; ++n) acc[f][n] = {0.f, 0.f, 0.f, 0.f};

    const _Float16* wqp = wqu + (size_t)(ph * 2 + pw) * KS * COUT * 32;

#pragma unroll
    for (int ko = 0; ko < KS; ++ko) {
        int tap = (ko * 32) / CIN;
        int ci = (ko * 32) % CIN + grp * 8;
        int kd = tap >> 2, ih = (tap >> 1) & 1, iwk = tap & 1;

        int lcol = col + iwk + pw;
        int r0 = ih + ph;
        int cb = ((kd * IH + r0) * IW + lcol) * CIN + ci;
        half8 a[4];
#pragma unroll
        for (int f = 0; f < 4; ++f)
            a[f] = ldswz(lin, (cb + f * IW * CIN) * 2);

        half8 bfr[NCB];
#pragma unroll
        for (int n = 0; n < NCB; ++n)
            bfr[n] = *(const half8*)(wqp + ((ko * COUT + n * 16 + col) * 32 + grp * 8));
#pragma unroll
        for (int f = 0; f < 4; ++f)
#pragma unroll
            for (int n = 0; n < NCB; ++n)
                acc[f][n] = __builtin_amdgcn_mfma_f32_16x16x32_f16(a[f], bfr[n],
                                                                   acc[f][n], 0, 0, 0);
    }

    const size_t obase = (size_t)bz * S * S * COUT;
#pragma unroll
    for (int n = 0; n < NCB; ++n) {
        int co = n * 16 + col;
        float sh = bnsh[co];
#pragma unroll
        for (int f = 0; f < 4; ++f) {
            int h = 2 * (bhp + f) + ph;
#pragma unroll
            for (int r = 0; r < 4; ++r) {
                int w = 2 * (bwp + grp * 4 + r) + pw;
                float y = acc[f][n][r] + sh;
                float v = (n < NCB / 2) ? fast_tanh(y) : fast_sigmoid(y);
                gout[obase + ((size_t)h * S + w) * COUT + co] = (_Float16)v;
            }
        }
    }
}

// ---------------- UNFUSED non-upsample conv (layer 2) ----------------
template <int CIN, int COUT, int S, int KSTEPS>
__global__ __launch_bounds__(256, 2) void conv_mfma(
    const _Float16* __restrict__ inp,   // [B*DD][S][S][CIN] f16
    const _Float16* __restrict__ wq,    // [KSTEPS][COUT][32] f16
    const float* __restrict__ bnsh,
    _Float16* __restrict__ gout) {      // [B*DD][S][S][COUT] f16

    constexpr int IH = 18;
    constexpr int IW = 18;
    constexpr int NCB = COUT / 16;
    constexpr int NC8 = CIN / 8;
    constexpr int PATCH = 3 * IH * IW;

    __shared__ __align__(16) _Float16 lin[PATCH * CIN];

    const int tid = threadIdx.x;
    const int lane = tid & 63;
    const int wv = tid >> 6;
    const int col = lane & 15;
    const int grp = lane >> 4;

    const int w0 = blockIdx.x * 16;
    const int h0 = blockIdx.y * 16;
    const int bz = blockIdx.z;
    const int d = bz % DD;

    const int ibh = h0 - 1;
    const int ibw = w0 - 1;

    for (int idx = tid; idx < PATCH * NC8; idx += 256) {
        int c8 = idx % NC8;
        int pos = idx / NC8;
        int iw = pos % IW, t = pos / IW;
        int ih = t % IH, kd = t / IH;
        int dz = d + kd - 1, gh = ibh + ih, gw = ibw + iw;
        half8 v = {0, 0, 0, 0, 0, 0, 0, 0};
        if ((unsigned)dz < (unsigned)DD && (unsigned)gh < (unsigned)S &&
            (unsigned)gw < (unsigned)S)
            v = *(const half8*)(inp +
                (((size_t)(bz + kd - 1) * S + gh) * S + gw) * CIN + c8 * 8);
        *(half8*)((char*)lin + swz((pos * CIN + c8 * 8) * 2)) = v;
    }
    __syncthreads();

    f32x4 acc[4][NCB];
#pragma unroll
    for (int f = 0; f < 4; ++f)
#pragma unroll
        for (int n = 0; n < NCB; ++n) acc[f][n] = {0.f, 0.f, 0.f, 0.f};

#pragma unroll
    for (int ko = 0; ko < KSTEPS; ++ko) {
        int tap = (ko * 32) / CIN;                  // literal after unroll (CIN>=32)
        int kd = tap / 9, kh = (tap / 3) % 3, kw = tap % 3;
        int ci = (ko * 32) % CIN + grp * 8;

        half8 a[4];
        int iw = col + kw;
        int cb = ((kd * IH + wv * 4 + kh) * IW + iw) * CIN + ci;
#pragma unroll
        for (int f = 0; f < 4; ++f)
            a[f] = ldswz(lin, (cb + f * IW * CIN) * 2);

        half8 bfr[NCB];
#pragma unroll
        for (int n = 0; n < NCB; ++n)
            bfr[n] = *(const half8*)(wq + ((ko * COUT + n * 16 + col) * 32 + grp * 8));
#pragma unroll
        for (int f = 0; f < 4; ++f)
#pragma unroll
            for (int n = 0; n < NCB; ++n)
                acc[f][n] = __builtin_amdgcn_mfma_f32_16x16x32_f16(a[f], bfr[n],
                                                                   acc[f][n], 0, 0, 0);
    }

    const size_t obase = (size_t)bz * S * S * COUT;
#pragma unroll
    for (int n = 0; n < NCB; ++n) {
        int co = n * 16 + col;
        float sh = bnsh[co];
#pragma unroll
        for (int f = 0; f < 4; ++f) {
            int h = h0 + wv * 4 + f;
#pragma unroll
            for (int r = 0; r < 4; ++r) {
                int w = w0 + grp * 4 + r;
                float y = acc[f][n][r] + sh;
                float v = (n < NCB / 2) ? fast_tanh(y) : fast_sigmoid(y);
                gout[obase + ((size_t)h * S + w) * COUT + co] = (_Float16)v;
            }
        }
    }
}

// ---------------- qrnn scan (+skip add), layers 1,2 ----------------
template <int H, int HW>
__global__ __launch_bounds__(256) void qscan(
    const _Float16* __restrict__ g, const float* __restrict__ xs,
    _Float16* __restrict__ hout, int rev) {
    constexpr int NCB = H / 8;
    int idx = blockIdx.x * 256 + threadIdx.x;
    if (idx >= BB * HW * NCB) return;
    int cb = idx % NCB;
    int hw = (idx / NCB) % HW;
    int b = idx / (NCB * HW);
    int c0 = cb * 8;

    float h[8];
#pragma unroll
    for (int j = 0; j < 8; ++j) h[j] = 0.f;

    for (int t = 0; t < DD; ++t) {
        int d = rev ? (DD - 1 - t) : t;
        const _Float16* gp = g + ((size_t)(b * DD + d) * HW + hw) * (2 * H);
        half8 z8 = *(const half8*)(gp + c0);
        half8 f8 = *(const half8*)(gp + H + c0);
        half8 o;
#pragma unroll
        for (int j = 0; j < 8; ++j) {
            float fv = (float)f8[j];
            h[j] = fv * h[j] + (1.f - fv) * (float)z8[j];
            o[j] = (_Float16)(h[j] + xs[(((size_t)b * H + c0 + j) * DD + d) * HW + hw]);
        }
        *(half8*)(hout + ((size_t)(b * DD + d) * HW + hw) * H + c0) = o;
    }
}

// ============ FUSED conv+scan, collapsed upsample, SINGLE PARITY (layer 3) ============
// xs is f16 NDHWC (pre-transposed) -> coalesced epilogue add.
template <int CIN, int S, int HID, int KS, int REV, int LAST>
__global__ __launch_bounds__(256, 2) void fconv_up1(
    const _Float16* __restrict__ inp,   // [B*DD][S/2][S/2][CIN] f16
    const _Float16* __restrict__ wq,    // [4][KS][2][16][32] f16
    const float* __restrict__ bnsh,
    const _Float16* __restrict__ xs,    // [B*DD][S*S][HID] f16
    _Float16* __restrict__ hout,
    float* __restrict__ fout) {

    constexpr int SIN = S / 2;
    constexpr int IW = 18;
    constexpr int IHP = 6;
    constexpr int NC8 = CIN / 8;
    constexpr int P8 = IHP * IW * NC8;
    constexpr int NST = (P8 + 255) / 256;
    constexpr int PLANEB = IHP * IW * CIN * 2;
    constexpr int LWB = 3 * PLANEB;
    constexpr int WH = KS * 1024;

    __shared__ __align__(16) _Float16 lds[(LWB / 2) + WH];

    const int tid = threadIdx.x;
    const int lane = tid & 63;
    const int wv = tid >> 6;
    const int col = lane & 15;
    const int grp = lane >> 4;

    const int bwp = blockIdx.x * 16;
    const int bhp = blockIdx.y * 4;
    const int par = blockIdx.z & 3;
    const int b = blockIdx.z >> 2;
    const int ph = par >> 1, pw = par & 1;
    const size_t bbase = (size_t)b * DD;

    const float shz = bnsh[col];
    const float shf = bnsh[HID + col];
    const int hc = col;
    const _Float16* wqb = wq + (size_t)par * KS * 1024;

    auto stage_now = [&](int dz) {
        int slot = (dz + 33) % 3;
        for (int idx = tid; idx < P8; idx += 256) {
            int c8 = idx % NC8;
            int pos = idx / NC8;
            int ih = pos / IW, iw = pos % IW;
            int gh = bhp - 1 + ih, gw = bwp - 1 + iw;
            half8 v = {0, 0, 0, 0, 0, 0, 0, 0};
            if ((unsigned)dz < (unsigned)DD && (unsigned)gh < (unsigned)SIN &&
                (unsigned)gw < (unsigned)SIN)
                v = *(const half8*)(inp + (((bbase + dz) * SIN + gh) * SIN + gw) * CIN + c8 * 8);
            stswz(lds, slot * PLANEB + (pos * CIN + c8 * 8) * 2, v);
        }
    };

    constexpr int dir = REV ? -1 : 1;
    const int d0 = REV ? DD - 1 : 0;
    stage_now(d0 - dir);
    stage_now(d0);
    stage_now(d0 + dir);
    for (int i = tid; i < WH / 8; i += 256) {
        half8 v = *(const half8*)(wqb + i * 8);
        stswz(lds, LWB + i * 16, v);
    }
    __syncthreads();

    float hst[4];
#pragma unroll
    for (int r = 0; r < 4; ++r) hst[r] = 0.f;

    for (int t = 0; t < DD; ++t) {
        const int d = d0 + dir * t;
        const int dzl = d + 2 * dir;
        const int sm = (d - 1 + 33) % 3;
        const int s0 = (d + 33) % 3;
        const int sp = (d + 1 + 33) % 3;
        const int scommit = REV ? sp : sm;

        half8 sv[NST];
#pragma unroll
        for (int i = 0; i < NST; ++i) {
            int idx = tid + i * 256;
            half8 v = {0, 0, 0, 0, 0, 0, 0, 0};
            if (idx < P8) {
                int c8 = idx % NC8;
                int pos = idx / NC8;
                int ih = pos / IW, iw = pos % IW;
                int gh = bhp - 1 + ih, gw = bwp - 1 + iw;
                if ((unsigned)dzl < (unsigned)DD && (unsigned)gh < (unsigned)SIN &&
                    (unsigned)gw < (unsigned)SIN)
                    v = *(const half8*)(inp +
                        (((bbase + dzl) * SIN + gh) * SIN + gw) * CIN + c8 * 8);
            }
            sv[i] = v;
        }

        f32x4 accz = {0.f, 0.f, 0.f, 0.f};
        f32x4 accf = {0.f, 0.f, 0.f, 0.f};
#pragma unroll
        for (int ko = 0; ko < KS; ++ko) {
            int tap = (ko * 32) / CIN;
            int ci = (ko * 32) % CIN + grp * 8;
            int kd = tap >> 2, ihh = (tap >> 1) & 1, iwk = tap & 1;
            int slot = kd == 0 ? sm : (kd == 1 ? s0 : sp);
            int lcol = col + iwk + pw;
            int row = wv + ihh + ph;
            half8 a = ldswz(lds, slot * PLANEB + ((row * IW + lcol) * CIN + ci) * 2);
            half8 bf0 = ldswz(lds, LWB + (ko * 1024 + col * 32 + grp * 8) * 2);
            half8 bf1 = ldswz(lds, LWB + (ko * 1024 + 512 + col * 32 + grp * 8) * 2);
            accz = __builtin_amdgcn_mfma_f32_16x16x32_f16(a, bf0, accz, 0, 0, 0);
            accf = __builtin_amdgcn_mfma_f32_16x16x32_f16(a, bf1, accf, 0, 0, 0);
        }

        __syncthreads();
#pragma unroll
        for (int i = 0; i < NST; ++i) {
            int idx = tid + i * 256;
            if (idx < P8) {
                int c8 = idx % NC8;
                int pos = idx / NC8;
                stswz(lds, scommit * PLANEB + (pos * CIN + c8 * 8) * 2, sv[i]);
            }
        }

        int h = 2 * (bhp + wv) + ph;
#pragma unroll
        for (int r = 0; r < 4; ++r) {
            int w = 2 * (bwp + grp * 4 + r) + pw;
            size_t sp2 = (size_t)h * S + w;
            float z = fast_tanh(accz[r] + shz);
            float fg = fast_sigmoid(accf[r] + shf);
            hst[r] = fg * hst[r] + (1.f - fg) * z;
            if (LAST) {
                fout[(((size_t)b * HID + hc) * DD + d) * ((size_t)S * S) + sp2] = hst[r];
            } else {
                float xv = (float)xs[((bbase + d) * ((size_t)S * S) + sp2) * HID + hc];
                hout[((bbase + d) * ((size_t)S * S) + sp2) * HID + hc] =
                    (_Float16)(hst[r] + xv);
            }
        }
        __syncthreads();
    }
}

// ============ FUSED conv+scan, non-upsample, CS=1, FULLW (layer 4) ============
template <int CIN, int S, int HID, int KS, int NF, int REV>
__global__ __launch_bounds__(256, 2) void fconv3(
    const _Float16* __restrict__ inp,   // [B*DD][S][S][CIN] f16
    const _Float16* __restrict__ wq,    // [KS][2][16][32] f16
    const float* __restrict__ bnsh,
    float* __restrict__ fout) {         // [B][HID][DD][S*S] f32

    constexpr int IW = 18;
    constexpr int TH = 4 * NF;
    constexpr int IHP = TH + 2;
    constexpr int NC8 = CIN / 8;
    constexpr int P8 = IHP * IW * NC8;
    constexpr int NST = (P8 + 255) / 256;
    constexpr int PLANEB = IHP * IW * CIN * 2;
    constexpr int LWB = 3 * PLANEB;
    constexpr int WH = KS * 1024;

    __shared__ __align__(16) _Float16 lds[(LWB / 2) + WH];

    const int tid = threadIdx.x;
    const int lane = tid & 63;
    const int wv = tid >> 6;
    const int col = lane & 15;
    const int grp = lane >> 4;

    const int w0 = blockIdx.x * 16;
    const int h0 = blockIdx.y * TH;
    const int b = blockIdx.z;
    const size_t bbase = (size_t)b * DD;

    const float shz = bnsh[col];
    const float shf = bnsh[HID + col];
    const int hc = col;

    auto stage_now = [&](int dz) {
        int slot = (dz + 33) % 3;
        for (int idx = tid; idx < P8; idx += 256) {
            int c8 = idx % NC8;
            int pos = idx / NC8;
            int ih = pos / IW, iw = pos % IW;
            int gh = h0 - 1 + ih, gw = w0 - 1 + iw;
            half8 v = {0, 0, 0, 0, 0, 0, 0, 0};
            if ((unsigned)dz < (unsigned)DD && (unsigned)gh < (unsigned)S &&
                (unsigned)gw < (unsigned)S)
                v = *(const half8*)(inp + (((bbase + dz) * S + gh) * S + gw) * CIN + c8 * 8);
            stswz(lds, slot * PLANEB + (pos * CIN + c8 * 8) * 2, v);
        }
    };

    constexpr int dir = REV ? -1 : 1;
    const int d0 = REV ? DD - 1 : 0;
    stage_now(d0 - dir);
    stage_now(d0);
    stage_now(d0 + dir);
    for (int i = tid; i < WH / 8; i += 256) {
        half8 v = *(const half8*)(wq + i * 8);
        stswz(lds, LWB + i * 16, v);
    }
    __syncthreads();

    float hst[NF][4];
#pragma unroll
    for (int f = 0; f < NF; ++f)
#pragma unroll
        for (int r = 0; r < 4; ++r) hst[f][r] = 0.f;

    for (int t = 0; t < DD; ++t) {
        const int d = d0 + dir * t;
        const int dzl = d + 2 * dir;
        const int sm = (d - 1 + 33) % 3;
        const int s0 = (d + 33) % 3;
        const int sp = (d + 1 + 33) % 3;
        const int scommit = REV ? sp : sm;

        half8 sv[NST];
#pragma unroll
        for (int i = 0; i < NST; ++i) {
            int idx = tid + i * 256;
            half8 v = {0, 0, 0, 0, 0, 0, 0, 0};
            if (idx < P8) {
                int c8 = idx % NC8;
                int pos = idx / NC8;
                int ih = pos / IW, iw = pos % IW;
                int gh = h0 - 1 + ih, gw = w0 - 1 + iw;
                if ((unsigned)dzl < (unsigned)DD && (unsigned)gh < (unsigned)S &&
                    (unsigned)gw < (unsigned)S)
                    v = *(const half8*)(inp +
                        (((bbase + dzl) * S + gh) * S + gw) * CIN + c8 * 8);
            }
            sv[i] = v;
        }

        f32x4 acc[NF][2];
#pragma unroll
        for (int f = 0; f < NF; ++f) {
            acc[f][0] = {0.f, 0.f, 0.f, 0.f};
            acc[f][1] = {0.f, 0.f, 0.f, 0.f};
        }
#pragma unroll
        for (int ko = 0; ko < KS; ++ko) {
            int kd, kh, kw, ci;
            if (CIN >= 32) {
                int tap = (ko * 32) / CIN;
                kd = tap / 9; kh = (tap / 3) % 3; kw = tap % 3;
                ci = (ko * 32) % CIN + grp * 8;
            } else {                                // CIN==16: 2 taps per k-step
                int t0 = (2 * ko < 27) ? 2 * ko : 26;
                int t1 = (2 * ko + 1 < 27) ? 2 * ko + 1 : 26;
                int hi = grp >> 1;
                kd = hi ? t1 / 9 : t0 / 9;
                kh = hi ? (t1 / 3) % 3 : (t0 / 3) % 3;
                kw = hi ? t1 % 3 : t0 % 3;
                ci = (grp & 1) * 8;
            }
            int slot = kd == 0 ? sm : (kd == 1 ? s0 : sp);
            int iw = col + kw;
            half8 a[NF];
#pragma unroll
            for (int f = 0; f < NF; ++f)
                a[f] = ldswz(lds, slot * PLANEB +
                             (((wv * NF + f + kh) * IW + iw) * CIN + ci) * 2);
            half8 bf0 = ldswz(lds, LWB + (ko * 1024 + col * 32 + grp * 8) * 2);
            half8 bf1 = ldswz(lds, LWB + (ko * 1024 + 512 + col * 32 + grp * 8) * 2);
#pragma unroll
            for (int f = 0; f < NF; ++f) {
                acc[f][0] = __builtin_amdgcn_mfma_f32_16x16x32_f16(a[f], bf0, acc[f][0], 0, 0, 0);
                acc[f][1] = __builtin_amdgcn_mfma_f32_16x16x32_f16(a[f], bf1, acc[f][1], 0, 0, 0);
            }
        }

        __syncthreads();
#pragma unroll
        for (int i = 0; i < NST; ++i) {
            int idx = tid + i * 256;
            if (idx < P8) {
                int c8 = idx % NC8;
                int pos = idx / NC8;
                stswz(lds, scommit * PLANEB + (pos * CIN + c8 * 8) * 2, sv[i]);
            }
        }

#pragma unroll
        for (int f = 0; f < NF; ++f) {
            int h = h0 + wv * NF + f;
#pragma unroll
            for (int r = 0; r < 4; ++r) {
                int w = w0 + grp * 4 + r;
                size_t sp2 = (size_t)h * S + w;
                float z = fast_tanh(acc[f][0][r] + shz);
                float fg = fast_sigmoid(acc[f][1][r] + shf);
                hst[f][r] = fg * hst[f][r] + (1.f - fg) * z;
                fout[(((size_t)b * HID + hc) * DD + d) * ((size_t)S * S) + sp2] = hst[f][r];
            }
        }
        __syncthreads();
    }
}

extern "C" void kernel_launch(void* const* d_in, const int* in_sizes, int n_in,
                              void* d_out, int out_size, void* d_ws, size_t ws_size,
                              hipStream_t stream) {
    const float* x   = (const float*)d_in[0];
    const float* xs0 = (const float*)d_in[1];
    const float* xs1 = (const float*)d_in[2];
    const float* xs2 = (const float*)d_in[3];
    const float* w0  = (const float*)d_in[4];
    const float* w1  = (const float*)d_in[5];
    const float* w2  = (const float*)d_in[6];
    const float* w3  = (const float*)d_in[7];
    const float* bn0 = (const float*)d_in[8];
    const float* bn1 = (const float*)d_in[9];
    const float* bn2 = (const float*)d_in[10];
    const float* bn3 = (const float*)d_in[11];
    float* out = (float*)d_out;

    // ---- workspace layout ----
    char* p = (char*)d_ws;
    _Float16* xf   = (_Float16*)p; p += (size_t)124 * 1024 * 64 * 2;    // 16.25 MB
    _Float16* gA   = (_Float16*)p; p += (size_t)124 * 4096 * 64 * 2;    // 65 MB (gates L1/L2)
    _Float16* hA   = (_Float16*)p; p += (size_t)124 * 4096 * 32 * 2;    // 32.5 MB (h1+xs2)
    _Float16* hA2  = (_Float16*)p; p += (size_t)124 * 4096 * 32 * 2;    // 32.5 MB (h2+xs1)
    _Float16* hB   = (_Float16*)p; p += (size_t)124 * 16384 * 16 * 2;   // 65 MB   (h3+xs0)
    _Float16* xs0f = (_Float16*)p; p += (size_t)124 * 16384 * 16 * 2;   // 65 MB
    _Float16* wq0u = (_Float16*)p; p += (size_t)4 * 24 * 64 * 32 * 2;   // 384 KB
    _Float16* wq1  = (_Float16*)p; p += (size_t)27 * 64 * 32 * 2;       // 110 KB
    _Float16* wq2u = (_Float16*)p; p += (size_t)4 * 12 * 1024 * 2;      // 96 KB
    _Float16* wq3  = (_Float16*)p; p += (size_t)14 * 1024 * 2;          // 28 KB
    float* sh0 = (float*)p; p += 64 * 4;
    float* sh1 = (float*)p; p += 64 * 4;
    float* sh2 = (float*)p; p += 64 * 4;
    float* sh3 = (float*)p; p += 64 * 4;

    // ---- prep ----
    xconv<<<(4 * 31 * 1024 * 8 + 255) / 256, 256, 0, stream>>>(x, xf);
    xst<16, 16384><<<dim3(64, BB * DD), 256, 0, stream>>>(xs0, xs0f);
    wprep_upA<<<(4 * 24 * 32 * 64 + 255) / 256, 256, 0, stream>>>(w0, bn0, wq0u, 64, 64);
    wprepA<<<(27 * 32 * 64 + 255) / 256, 256, 0, stream>>>(w1, bn1, wq1, 32, 64, 27, 1);
    wprep_upB<<<(4 * 12 * 1024 + 255) / 256, 256, 0, stream>>>(w2, bn2, wq2u, 32, 32, 12);
    wprepC<<<(14 * 1024 + 255) / 256, 256, 0, stream>>>(w3, bn3, wq3, 16, 32, 14, 1);
    bnprep<<<1, 64, 0, stream>>>(bn0, 64, sh0);
    bnprep<<<1, 64, 0, stream>>>(bn1, 64, sh1);
    bnprep<<<1, 64, 0, stream>>>(bn2, 32, sh2);
    bnprep<<<1, 64, 0, stream>>>(bn3, 32, sh3);

    // ---- layer 1 (UNFUSED): up(x) -> conv w0 (64->64) @64; fwd scan; hA = h1+xs2 ----
    conv_up<64, 64, 64, 3><<<dim3(2, 8, BB * DD), 256, 0, stream>>>(xf, wq0u, sh0, gA);
    qscan<32, 4096><<<(BB * 4096 * 4 + 255) / 256, 256, 0, stream>>>(gA, xs2, hA, 0);

    // ---- layer 2 (UNFUSED): deconv w1 (32->64) @64; rev scan; hA2 = h2+xs1 ----
    conv_mfma<32, 64, 64, 27><<<dim3(4, 4, BB * DD), 256, 0, stream>>>(hA, wq1, sh1, gA);
    qscan<32, 4096><<<(BB * 4096 * 4 + 255) / 256, 256, 0, stream>>>(gA, xs1, hA2, 1);

    // ---- layer 3 (FUSED, single-parity): up -> conv w2 (32->32) @128, fwd scan; hB = h3+xs0f ----
    fconv_up1<32, 128, 16, 12, 0, 0><<<dim3(4, 16, BB * 4), 256, 0, stream>>>(
        hA2, wq2u, sh2, xs0f, hB, nullptr);

    // ---- layer 4 (FUSED): deconv w3 (16->32) @128, rev scan; out fp32 NCDHW ----
    fconv3<16, 128, 16, 14, 2, 1><<<dim3(8, 16, BB), 256, 0, stream>>>(
        hB, wq3, sh3, out);
}

// Round 12
// 508.300 us; speedup vs baseline: 1.0056x; 1.0056x over previous
//
#include <hip/hip_runtime.h>
#include <math.h>

#define BB 4
#define DD 31

typedef _Float16 half8 __attribute__((ext_vector_type(8)));
typedef float f32x4 __attribute__((ext_vector_type(4)));

__device__ __forceinline__ int swz(int b) { return b ^ (((b >> 7) & 7) << 4); }
__device__ __forceinline__ half8 ldswz(const _Float16* lin, int byteoff) {
    return *(const half8*)((const char*)lin + swz(byteoff));
}
__device__ __forceinline__ void stswz(_Float16* lin, int byteoff, half8 v) {
    *(half8*)((char*)lin + swz(byteoff)) = v;
}
__device__ __forceinline__ float fast_tanh(float y) {
    float e = __expf(2.f * y);
    return 1.f - 2.f * __builtin_amdgcn_rcpf(e + 1.f);
}
__device__ __forceinline__ float fast_sigmoid(float y) {
    return __builtin_amdgcn_rcpf(1.f + __expf(-y));
}

// ---------------- prep kernels ----------------

__global__ void bnprep(const float* __restrict__ bn, int C, float* __restrict__ sh) {
    int c = threadIdx.x;
    if (c >= C) return;
    float g = bn[c], b = bn[C + c], m = bn[2 * C + c], v = bn[3 * C + c];
    sh[c] = b - m * (g * rsqrtf(v + 1e-5f));
}

// r5 layout: dst[ko][co][ki]; k = ko*32+ki = tap*CIN+ci, zero-pad k>=27*CIN
// tr=0: W = src[co][ci][tap]; tr=1 (deconv): W = src[ci][co][26-tap]. BN scale folded.
__global__ void wprepA(const float* __restrict__ src, const float* __restrict__ bn,
                       _Float16* __restrict__ dst, int CIN, int COUT, int KS, int tr) {
    int idx = blockIdx.x * 256 + threadIdx.x;
    int total = KS * 32 * COUT;
    if (idx >= total) return;
    int ki = idx % 32;
    int co = (idx / 32) % COUT;
    int ko = idx / (32 * COUT);
    int k = ko * 32 + ki;
    float v = 0.f;
    if (k < 27 * CIN) {
        int tap = k / CIN, ci = k % CIN;
        v = tr ? src[((size_t)ci * COUT + co) * 27 + (26 - tap)]
               : src[((size_t)co * CIN + ci) * 27 + tap];
        v *= bn[co] * rsqrtf(bn[3 * COUT + co] + 1e-5f);
    }
    dst[((size_t)ko * COUT + co) * 32 + ki] = (_Float16)v;
}

// fused layout (CS=1): dst[ko][n][c16][ki]; co = n*(COUT/2)+c16
__global__ void wprepC(const float* __restrict__ src, const float* __restrict__ bn,
                       _Float16* __restrict__ dst, int CIN, int COUT, int KS, int tr) {
    int idx = blockIdx.x * 256 + threadIdx.x;
    int total = KS * 1024;
    if (idx >= total) return;
    int ki = idx & 31;
    int c16 = (idx >> 5) & 15;
    int n = (idx >> 9) & 1;
    int ko = idx >> 10;
    int co = n * (COUT / 2) + c16;
    int k = ko * 32 + ki;
    float v = 0.f;
    if (k < 27 * CIN) {
        int tap = k / CIN, ci = k % CIN;
        v = tr ? src[((size_t)ci * COUT + co) * 27 + (26 - tap)]
               : src[((size_t)co * CIN + ci) * 27 + tap];
        v *= bn[co] * rsqrtf(bn[3 * COUT + co] + 1e-5f);
    }
    dst[idx] = (_Float16)v;
}

// collapsed upsample weights, r5 layout (unfused conv_up, L1):
// dst[par][ko][co][ki]; tap = (kd*2+ih)*2+iw (12 taps)
__global__ void wprep_upA(const float* __restrict__ src, const float* __restrict__ bn,
                          _Float16* __restrict__ dst, int CIN, int COUT) {
    const int KS = 12 * CIN / 32;
    int idx = blockIdx.x * 256 + threadIdx.x;
    int total = 4 * KS * 32 * COUT;
    if (idx >= total) return;
    int ki = idx % 32;
    int co = (idx / 32) % COUT;
    int ko = (idx / (32 * COUT)) % KS;
    int par = idx / (32 * COUT * KS);
    int k = ko * 32 + ki;
    int ci = k % CIN, tap = k / CIN;
    int kd = tap >> 2, ih = (tap >> 1) & 1, iw = tap & 1;
    int ph = par >> 1, pw = par & 1;
    const float c[2][2][3] = {{{1, 0, 0}, {0, 1, 1}}, {{1, 1, 0}, {0, 0, 1}}};
    float v = 0.f;
    for (int kh = 0; kh < 3; ++kh)
        for (int kw = 0; kw < 3; ++kw)
            v += c[ph][ih][kh] * c[pw][iw][kw] *
                 src[((size_t)co * CIN + ci) * 27 + kd * 9 + kh * 3 + kw];
    v *= bn[co] * rsqrtf(bn[3 * COUT + co] + 1e-5f);
    dst[(((size_t)par * KS + ko) * COUT + co) * 32 + ki] = (_Float16)v;
}

// collapsed upsample weights, fused layout (fconv_up1, L3): dst[par][ko][n][c16][ki]
__global__ void wprep_upB(const float* __restrict__ src, const float* __restrict__ bn,
                          _Float16* __restrict__ dst, int CIN, int COUT, int KS) {
    int idx = blockIdx.x * 256 + threadIdx.x;
    int total = 4 * KS * 1024;
    if (idx >= total) return;
    int ki = idx & 31;
    int c16 = (idx >> 5) & 15;
    int n = (idx >> 9) & 1;
    int ko = (idx >> 10) % KS;
    int par = idx / (KS * 1024);
    int co = n * (COUT / 2) + c16;
    int k = ko * 32 + ki;
    int ci = k % CIN, tap = k / CIN;
    int kd = tap >> 2, ih = (tap >> 1) & 1, iw = tap & 1;
    int ph = par >> 1, pw = par & 1;
    const float c[2][2][3] = {{{1, 0, 0}, {0, 1, 1}}, {{1, 1, 0}, {0, 0, 1}}};
    float v = 0.f;
    for (int kh = 0; kh < 3; ++kh)
        for (int kw = 0; kw < 3; ++kw)
            v += c[ph][ih][kh] * c[pw][iw][kw] *
                 src[((size_t)co * CIN + ci) * 27 + kd * 9 + kh * 3 + kw];
    v *= bn[co] * rsqrtf(bn[3 * COUT + co] + 1e-5f);
    dst[idx] = (_Float16)v;
}

// x [4][64][31][1024] f32 NCDHW -> xf [4*31][1024][64] f16 NDHWC
__global__ __launch_bounds__(256) void xconv(const float* __restrict__ src,
                                             _Float16* __restrict__ dst) {
    int idx = blockIdx.x * 256 + threadIdx.x;
    if (idx >= 4 * 31 * 1024 * 8) return;
    int cb = idx & 7;
    int pos = (idx >> 3) & 1023;
    int bd = idx >> 13;
    int d = bd % 31, b = bd / 31;
    half8 v;
#pragma unroll
    for (int j = 0; j < 8; ++j)
        v[j] = (_Float16)src[(((size_t)b * 64 + cb * 8 + j) * 31 + d) * 1024 + pos];
    *(half8*)(dst + ((size_t)bd * 1024 + pos) * 64 + cb * 8) = v;
}

// xs f32 [B][C][DD][HW] -> f16 [B*DD][HW][C]  (coalesced reads per channel,
// per-thread contiguous C*2-byte write)
template <int C, int HW>
__global__ __launch_bounds__(256) void xst(const float* __restrict__ src,
                                           _Float16* __restrict__ dst) {
    int hw = blockIdx.x * 256 + threadIdx.x;
    int bd = blockIdx.y;
    int d = bd % DD, b = bd / DD;
    _Float16 tmp[C];
#pragma unroll
    for (int c = 0; c < C; ++c)
        tmp[c] = (_Float16)src[((size_t)(b * C + c) * DD + d) * HW + hw];
#pragma unroll
    for (int c8 = 0; c8 < C / 8; ++c8)
        *(half8*)(dst + ((size_t)bd * HW + hw) * C + c8 * 8) = *(half8*)(tmp + c8 * 8);
}

// ---------------- UNFUSED collapsed upsample conv (layer 1) ----------------
template <int CIN, int COUT, int S, int MINW>
__global__ __launch_bounds__(256, MINW) void conv_up(
    const _Float16* __restrict__ inp,   // [B*DD][S/2][S/2][CIN] f16
    const _Float16* __restrict__ wqu,   // [4][KS][COUT][32] f16
    const float* __restrict__ bnsh,
    _Float16* __restrict__ gout) {      // [B*DD][S][S][COUT] f16

    constexpr int SIN = S / 2;
    constexpr int KS = 12 * CIN / 32;
    constexpr int NCB = COUT / 16;
    constexpr int NC8 = CIN / 8;
    constexpr int IH = 6, IW = 18;
    constexpr int PATCH = 3 * IH * IW;

    __shared__ __align__(16) _Float16 lin[PATCH * CIN];

    const int tid = threadIdx.x;
    const int lane = tid & 63;
    const int wv = tid >> 6;
    const int col = lane & 15;
    const int grp = lane >> 4;
    const int ph = wv >> 1, pw = wv & 1;

    const int bwp = blockIdx.x * 16;
    const int bhp = blockIdx.y * 4;
    const int bz = blockIdx.z;
    const int d = bz % DD;

    for (int idx = tid; idx < PATCH * NC8; idx += 256) {
        int c8 = idx % NC8;
        int pos = idx / NC8;
        int iwp = pos % IW, t = pos / IW;
        int ihp = t % IH, kd = t / IH;
        int dz = d + kd - 1, gh = bhp - 1 + ihp, gw = bwp - 1 + iwp;
        half8 v = {0, 0, 0, 0, 0, 0, 0, 0};
        if ((unsigned)dz < (unsigned)DD && (unsigned)gh < (unsigned)SIN &&
            (unsigned)gw < (unsigned)SIN)
            v = *(const half8*)(inp +
                (((size_t)(bz + kd - 1) * SIN + gh) * SIN + gw) * CIN + c8 * 8);
        *(half8*)((char*)lin + swz((pos * CIN + c8 * 8) * 2)) = v;
    }
    __syncthreads();

    f32x4 acc[4][NCB];
#pragma unroll
    for (int f = 0; f < 4; ++f)
#pragma unroll
        for (int n = 0; n < NCB; ++n) acc[f][n] = {0.f, 0.f, 0.f, 0.f};

    const _Float16* wqp = wqu + (size_t)(ph * 2 + pw) * KS * COUT * 32;

#pragma unroll
    for (int ko = 0; ko < KS; ++ko) {
        int tap = (ko * 32) / CIN;
        int ci = (ko * 32) % CIN + grp * 8;
        int kd = tap >> 2, ih = (tap >> 1) & 1, iwk = tap & 1;

        int lcol = col + iwk + pw;
        int r0 = ih + ph;
        int cb = ((kd * IH + r0) * IW + lcol) * CIN + ci;
        half8 a[4];
#pragma unroll
        for (int f = 0; f < 4; ++f)
            a[f] = ldswz(lin, (cb + f * IW * CIN) * 2);

        half8 bfr[NCB];
#pragma unroll
        for (int n = 0; n < NCB; ++n)
            bfr[n] = *(const half8*)(wqp + ((ko * COUT + n * 16 + col) * 32 + grp * 8));
#pragma unroll
        for (int f = 0; f < 4; ++f)
#pragma unroll
            for (int n = 0; n < NCB; ++n)
                acc[f][n] = __builtin_amdgcn_mfma_f32_16x16x32_f16(a[f], bfr[n],
                                                                   acc[f][n], 0, 0, 0);
    }

    const size_t obase = (size_t)bz * S * S * COUT;
#pragma unroll
    for (int n = 0; n < NCB; ++n) {
        int co = n * 16 + col;
        float sh = bnsh[co];
#pragma unroll
        for (int f = 0; f < 4; ++f) {
            int h = 2 * (bhp + f) + ph;
#pragma unroll
            for (int r = 0; r < 4; ++r) {
                int w = 2 * (bwp + grp * 4 + r) + pw;
                float y = acc[f][n][r] + sh;
                float v = (n < NCB / 2) ? fast_tanh(y) : fast_sigmoid(y);
                gout[obase + ((size_t)h * S + w) * COUT + co] = (_Float16)v;
            }
        }
    }
}

// ---------------- UNFUSED non-upsample conv (layer 2) ----------------
template <int CIN, int COUT, int S, int KSTEPS>
__global__ __launch_bounds__(256, 2) void conv_mfma(
    const _Float16* __restrict__ inp,   // [B*DD][S][S][CIN] f16
    const _Float16* __restrict__ wq,    // [KSTEPS][COUT][32] f16
    const float* __restrict__ bnsh,
    _Float16* __restrict__ gout) {      // [B*DD][S][S][COUT] f16

    constexpr int IH = 18;
    constexpr int IW = 18;
    constexpr int NCB = COUT / 16;
    constexpr int NC8 = CIN / 8;
    constexpr int PATCH = 3 * IH * IW;

    __shared__ __align__(16) _Float16 lin[PATCH * CIN];

    const int tid = threadIdx.x;
    const int lane = tid & 63;
    const int wv = tid >> 6;
    const int col = lane & 15;
    const int grp = lane >> 4;

    const int w0 = blockIdx.x * 16;
    const int h0 = blockIdx.y * 16;
    const int bz = blockIdx.z;
    const int d = bz % DD;

    const int ibh = h0 - 1;
    const int ibw = w0 - 1;

    for (int idx = tid; idx < PATCH * NC8; idx += 256) {
        int c8 = idx % NC8;
        int pos = idx / NC8;
        int iw = pos % IW, t = pos / IW;
        int ih = t % IH, kd = t / IH;
        int dz = d + kd - 1, gh = ibh + ih, gw = ibw + iw;
        half8 v = {0, 0, 0, 0, 0, 0, 0, 0};
        if ((unsigned)dz < (unsigned)DD && (unsigned)gh < (unsigned)S &&
            (unsigned)gw < (unsigned)S)
            v = *(const half8*)(inp +
                (((size_t)(bz + kd - 1) * S + gh) * S + gw) * CIN + c8 * 8);
        *(half8*)((char*)lin + swz((pos * CIN + c8 * 8) * 2)) = v;
    }
    __syncthreads();

    f32x4 acc[4][NCB];
#pragma unroll
    for (int f = 0; f < 4; ++f)
#pragma unroll
        for (int n = 0; n < NCB; ++n) acc[f][n] = {0.f, 0.f, 0.f, 0.f};

#pragma unroll
    for (int ko = 0; ko < KSTEPS; ++ko) {
        int tap = (ko * 32) / CIN;                  // literal after unroll (CIN>=32)
        int kd = tap / 9, kh = (tap / 3) % 3, kw = tap % 3;
        int ci = (ko * 32) % CIN + grp * 8;

        half8 a[4];
        int iw = col + kw;
        int cb = ((kd * IH + wv * 4 + kh) * IW + iw) * CIN + ci;
#pragma unroll
        for (int f = 0; f < 4; ++f)
            a[f] = ldswz(lin, (cb + f * IW * CIN) * 2);

        half8 bfr[NCB];
#pragma unroll
        for (int n = 0; n < NCB; ++n)
            bfr[n] = *(const half8*)(wq + ((ko * COUT + n * 16 + col) * 32 + grp * 8));
#pragma unroll
        for (int f = 0; f < 4; ++f)
#pragma unroll
            for (int n = 0; n < NCB; ++n)
                acc[f][n] = __builtin_amdgcn_mfma_f32_16x16x32_f16(a[f], bfr[n],
                                                                   acc[f][n], 0, 0, 0);
    }

    const size_t obase = (size_t)bz * S * S * COUT;
#pragma unroll
    for (int n = 0; n < NCB; ++n) {
        int co = n * 16 + col;
        float sh = bnsh[co];
#pragma unroll
        for (int f = 0; f < 4; ++f) {
            int h = h0 + wv * 4 + f;
#pragma unroll
            for (int r = 0; r < 4; ++r) {
                int w = w0 + grp * 4 + r;
                float y = acc[f][n][r] + sh;
                float v = (n < NCB / 2) ? fast_tanh(y) : fast_sigmoid(y);
                gout[obase + ((size_t)h * S + w) * COUT + co] = (_Float16)v;
            }
        }
    }
}

// ---------------- qrnn scan (+skip add), layers 1,2 ----------------
template <int H, int HW>
__global__ __launch_bounds__(256) void qscan(
    const _Float16* __restrict__ g, const float* __restrict__ xs,
    _Float16* __restrict__ hout, int rev) {
    constexpr int NCB = H / 8;
    int idx = blockIdx.x * 256 + threadIdx.x;
    if (idx >= BB * HW * NCB) return;
    int cb = idx % NCB;
    int hw = (idx / NCB) % HW;
    int b = idx / (NCB * HW);
    int c0 = cb * 8;

    float h[8];
#pragma unroll
    for (int j = 0; j < 8; ++j) h[j] = 0.f;

    for (int t = 0; t < DD; ++t) {
        int d = rev ? (DD - 1 - t) : t;
        const _Float16* gp = g + ((size_t)(b * DD + d) * HW + hw) * (2 * H);
        half8 z8 = *(const half8*)(gp + c0);
        half8 f8 = *(const half8*)(gp + H + c0);
        half8 o;
#pragma unroll
        for (int j = 0; j < 8; ++j) {
            float fv = (float)f8[j];
            h[j] = fv * h[j] + (1.f - fv) * (float)z8[j];
            o[j] = (_Float16)(h[j] + xs[(((size_t)b * H + c0 + j) * DD + d) * HW + hw]);
        }
        *(half8*)(hout + ((size_t)(b * DD + d) * HW + hw) * H + c0) = o;
    }
}

// ============ FUSED conv+scan, collapsed upsample, SINGLE PARITY (layer 3) ============
// xs is f16 NDHWC (pre-transposed) -> coalesced epilogue add.
template <int CIN, int S, int HID, int KS, int REV, int LAST>
__global__ __launch_bounds__(256, 2) void fconv_up1(
    const _Float16* __restrict__ inp,   // [B*DD][S/2][S/2][CIN] f16
    const _Float16* __restrict__ wq,    // [4][KS][2][16][32] f16
    const float* __restrict__ bnsh,
    const _Float16* __restrict__ xs,    // [B*DD][S*S][HID] f16
    _Float16* __restrict__ hout,
    float* __restrict__ fout) {

    constexpr int SIN = S / 2;
    constexpr int IW = 18;
    constexpr int IHP = 6;
    constexpr int NC8 = CIN / 8;
    constexpr int P8 = IHP * IW * NC8;
    constexpr int NST = (P8 + 255) / 256;
    constexpr int PLANEB = IHP * IW * CIN * 2;
    constexpr int LWB = 3 * PLANEB;
    constexpr int WH = KS * 1024;

    __shared__ __align__(16) _Float16 lds[(LWB / 2) + WH];

    const int tid = threadIdx.x;
    const int lane = tid & 63;
    const int wv = tid >> 6;
    const int col = lane & 15;
    const int grp = lane >> 4;

    const int bwp = blockIdx.x * 16;
    const int bhp = blockIdx.y * 4;
    const int par = blockIdx.z & 3;
    const int b = blockIdx.z >> 2;
    const int ph = par >> 1, pw = par & 1;
    const size_t bbase = (size_t)b * DD;

    const float shz = bnsh[col];
    const float shf = bnsh[HID + col];
    const int hc = col;
    const _Float16* wqb = wq + (size_t)par * KS * 1024;

    auto stage_now = [&](int dz) {
        int slot = (dz + 33) % 3;
        for (int idx = tid; idx < P8; idx += 256) {
            int c8 = idx % NC8;
            int pos = idx / NC8;
            int ih = pos / IW, iw = pos % IW;
            int gh = bhp - 1 + ih, gw = bwp - 1 + iw;
            half8 v = {0, 0, 0, 0, 0, 0, 0, 0};
            if ((unsigned)dz < (unsigned)DD && (unsigned)gh < (unsigned)SIN &&
                (unsigned)gw < (unsigned)SIN)
                v = *(const half8*)(inp + (((bbase + dz) * SIN + gh) * SIN + gw) * CIN + c8 * 8);
            stswz(lds, slot * PLANEB + (pos * CIN + c8 * 8) * 2, v);
        }
    };

    constexpr int dir = REV ? -1 : 1;
    const int d0 = REV ? DD - 1 : 0;
    stage_now(d0 - dir);
    stage_now(d0);
    stage_now(d0 + dir);
    for (int i = tid; i < WH / 8; i += 256) {
        half8 v = *(const half8*)(wqb + i * 8);
        stswz(lds, LWB + i * 16, v);
    }
    __syncthreads();

    float hst[4];
#pragma unroll
    for (int r = 0; r < 4; ++r) hst[r] = 0.f;

    for (int t = 0; t < DD; ++t) {
        const int d = d0 + dir * t;
        const int dzl = d + 2 * dir;
        const int sm = (d - 1 + 33) % 3;
        const int s0 = (d + 33) % 3;
        const int sp = (d + 1 + 33) % 3;
        const int scommit = REV ? sp : sm;

        half8 sv[NST];
#pragma unroll
        for (int i = 0; i < NST; ++i) {
            int idx = tid + i * 256;
            half8 v = {0, 0, 0, 0, 0, 0, 0, 0};
            if (idx < P8) {
                int c8 = idx % NC8;
                int pos = idx / NC8;
                int ih = pos / IW, iw = pos % IW;
                int gh = bhp - 1 + ih, gw = bwp - 1 + iw;
                if ((unsigned)dzl < (unsigned)DD && (unsigned)gh < (unsigned)SIN &&
                    (unsigned)gw < (unsigned)SIN)
                    v = *(const half8*)(inp +
                        (((bbase + dzl) * SIN + gh) * SIN + gw) * CIN + c8 * 8);
            }
            sv[i] = v;
        }

        f32x4 accz = {0.f, 0.f, 0.f, 0.f};
        f32x4 accf = {0.f, 0.f, 0.f, 0.f};
#pragma unroll
        for (int ko = 0; ko < KS; ++ko) {
            int tap = (ko * 32) / CIN;
            int ci = (ko * 32) % CIN + grp * 8;
            int kd = tap >> 2, ihh = (tap >> 1) & 1, iwk = tap & 1;
            int slot = kd == 0 ? sm : (kd == 1 ? s0 : sp);
            int lcol = col + iwk + pw;
            int row = wv + ihh + ph;
            half8 a = ldswz(lds, slot * PLANEB + ((row * IW + lcol) * CIN + ci) * 2);
            half8 bf0 = ldswz(lds, LWB + (ko * 1024 + col * 32 + grp * 8) * 2);
            half8 bf1 = ldswz(lds, LWB + (ko * 1024 + 512 + col * 32 + grp * 8) * 2);
            accz = __builtin_amdgcn_mfma_f32_16x16x32_f16(a, bf0, accz, 0, 0, 0);
            accf = __builtin_amdgcn_mfma_f32_16x16x32_f16(a, bf1, accf, 0, 0, 0);
        }

        __syncthreads();
#pragma unroll
        for (int i = 0; i < NST; ++i) {
            int idx = tid + i * 256;
            if (idx < P8) {
                int c8 = idx % NC8;
                int pos = idx / NC8;
                stswz(lds, scommit * PLANEB + (pos * CIN + c8 * 8) * 2, sv[i]);
            }
        }

        int h = 2 * (bhp + wv) + ph;
#pragma unroll
        for (int r = 0; r < 4; ++r) {
            int w = 2 * (bwp + grp * 4 + r) + pw;
            size_t sp2 = (size_t)h * S + w;
            float z = fast_tanh(accz[r] + shz);
            float fg = fast_sigmoid(accf[r] + shf);
            hst[r] = fg * hst[r] + (1.f - fg) * z;
            if (LAST) {
                fout[(((size_t)b * HID + hc) * DD + d) * ((size_t)S * S) + sp2] = hst[r];
            } else {
                float xv = (float)xs[((bbase + d) * ((size_t)S * S) + sp2) * HID + hc];
                hout[((bbase + d) * ((size_t)S * S) + sp2) * HID + hc] =
                    (_Float16)(hst[r] + xv);
            }
        }
        __syncthreads();
    }
}

// ============ FUSED conv+scan, non-upsample, CS=1, FULLW (layer 4) ============
template <int CIN, int S, int HID, int KS, int NF, int REV>
__global__ __launch_bounds__(256, 2) void fconv3(
    const _Float16* __restrict__ inp,   // [B*DD][S][S][CIN] f16
    const _Float16* __restrict__ wq,    // [KS][2][16][32] f16
    const float* __restrict__ bnsh,
    float* __restrict__ fout) {         // [B][HID][DD][S*S] f32

    constexpr int IW = 18;
    constexpr int TH = 4 * NF;
    constexpr int IHP = TH + 2;
    constexpr int NC8 = CIN / 8;
    constexpr int P8 = IHP * IW * NC8;
    constexpr int NST = (P8 + 255) / 256;
    constexpr int PLANEB = IHP * IW * CIN * 2;
    constexpr int LWB = 3 * PLANEB;
    constexpr int WH = KS * 1024;

    __shared__ __align__(16) _Float16 lds[(LWB / 2) + WH];

    const int tid = threadIdx.x;
    const int lane = tid & 63;
    const int wv = tid >> 6;
    const int col = lane & 15;
    const int grp = lane >> 4;

    const int w0 = blockIdx.x * 16;
    const int h0 = blockIdx.y * TH;
    const int b = blockIdx.z;
    const size_t bbase = (size_t)b * DD;

    const float shz = bnsh[col];
    const float shf = bnsh[HID + col];
    const int hc = col;

    auto stage_now = [&](int dz) {
        int slot = (dz + 33) % 3;
        for (int idx = tid; idx < P8; idx += 256) {
            int c8 = idx % NC8;
            int pos = idx / NC8;
            int ih = pos / IW, iw = pos % IW;
            int gh = h0 - 1 + ih, gw = w0 - 1 + iw;
            half8 v = {0, 0, 0, 0, 0, 0, 0, 0};
            if ((unsigned)dz < (unsigned)DD && (unsigned)gh < (unsigned)S &&
                (unsigned)gw < (unsigned)S)
                v = *(const half8*)(inp + (((bbase + dz) * S + gh) * S + gw) * CIN + c8 * 8);
            stswz(lds, slot * PLANEB + (pos * CIN + c8 * 8) * 2, v);
        }
    };

    constexpr int dir = REV ? -1 : 1;
    const int d0 = REV ? DD - 1 : 0;
    stage_now(d0 - dir);
    stage_now(d0);
    stage_now(d0 + dir);
    for (int i = tid; i < WH / 8; i += 256) {
        half8 v = *(const half8*)(wq + i * 8);
        stswz(lds, LWB + i * 16, v);
    }
    __syncthreads();

    float hst[NF][4];
#pragma unroll
    for (int f = 0; f < NF; ++f)
#pragma unroll
        for (int r = 0; r < 4; ++r) hst[f][r] = 0.f;

    for (int t = 0; t < DD; ++t) {
        const int d = d0 + dir * t;
        const int dzl = d + 2 * dir;
        const int sm = (d - 1 + 33) % 3;
        const int s0 = (d + 33) % 3;
        const int sp = (d + 1 + 33) % 3;
        const int scommit = REV ? sp : sm;

        half8 sv[NST];
#pragma unroll
        for (int i = 0; i < NST; ++i) {
            int idx = tid + i * 256;
            half8 v = {0, 0, 0, 0, 0, 0, 0, 0};
            if (idx < P8) {
                int c8 = idx % NC8;
                int pos = idx / NC8;
                int ih = pos / IW, iw = pos % IW;
                int gh = h0 - 1 + ih, gw = w0 - 1 + iw;
                if ((unsigned)dzl < (unsigned)DD && (unsigned)gh < (unsigned)S &&
                    (unsigned)gw < (unsigned)S)
                    v = *(const half8*)(inp +
                        (((bbase + dzl) * S + gh) * S + gw) * CIN + c8 * 8);
            }
            sv[i] = v;
        }

        f32x4 acc[NF][2];
#pragma unroll
        for (int f = 0; f < NF; ++f) {
            acc[f][0] = {0.f, 0.f, 0.f, 0.f};
            acc[f][1] = {0.f, 0.f, 0.f, 0.f};
        }
#pragma unroll
        for (int ko = 0; ko < KS; ++ko) {
            int kd, kh, kw, ci;
            if (CIN >= 32) {
                int tap = (ko * 32) / CIN;
                kd = tap / 9; kh = (tap / 3) % 3; kw = tap % 3;
                ci = (ko * 32) % CIN + grp * 8;
            } else {                                // CIN==16: 2 taps per k-step
                int t0 = (2 * ko < 27) ? 2 * ko : 26;
                int t1 = (2 * ko + 1 < 27) ? 2 * ko + 1 : 26;
                int hi = grp >> 1;
                kd = hi ? t1 / 9 : t0 / 9;
                kh = hi ? (t1 / 3) % 3 : (t0 / 3) % 3;
                kw = hi ? t1 % 3 : t0 % 3;
                ci = (grp & 1) * 8;
            }
            int slot = kd == 0 ? sm : (kd == 1 ? s0 : sp);
            int iw = col + kw;
            half8 a[NF];
#pragma unroll
            for (int f = 0; f < NF; ++f)
                a[f] = ldswz(lds, slot * PLANEB +
                             (((wv * NF + f + kh) * IW + iw) * CIN + ci) * 2);
            half8 bf0 = ldswz(lds, LWB + (ko * 1024 + col * 32 + grp * 8) * 2);
            half8 bf1 = ldswz(lds, LWB + (ko * 1024 + 512 + col * 32 + grp * 8) * 2);
#pragma unroll
            for (int f = 0; f < NF; ++f) {
                acc[f][0] = __builtin_amdgcn_mfma_f32_16x16x32_f16(a[f], bf0, acc[f][0], 0, 0, 0);
                acc[f][1] = __builtin_amdgcn_mfma_f32_16x16x32_f16(a[f], bf1, acc[f][1], 0, 0, 0);
            }
        }

        __syncthreads();
#pragma unroll
        for (int i = 0; i < NST; ++i) {
            int idx = tid + i * 256;
            if (idx < P8) {
                int c8 = idx % NC8;
                int pos = idx / NC8;
                stswz(lds, scommit * PLANEB + (pos * CIN + c8 * 8) * 2, sv[i]);
            }
        }

#pragma unroll
        for (int f = 0; f < NF; ++f) {
            int h = h0 + wv * NF + f;
#pragma unroll
            for (int r = 0; r < 4; ++r) {
                int w = w0 + grp * 4 + r;
                size_t sp2 = (size_t)h * S + w;
                float z = fast_tanh(acc[f][0][r] + shz);
                float fg = fast_sigmoid(acc[f][1][r] + shf);
                hst[f][r] = fg * hst[f][r] + (1.f - fg) * z;
                fout[(((size_t)b * HID + hc) * DD + d) * ((size_t)S * S) + sp2] = hst[f][r];
            }
        }
        __syncthreads();
    }
}

extern "C" void kernel_launch(void* const* d_in, const int* in_sizes, int n_in,
                              void* d_out, int out_size, void* d_ws, size_t ws_size,
                              hipStream_t stream) {
    const float* x   = (const float*)d_in[0];
    const float* xs0 = (const float*)d_in[1];
    const float* xs1 = (const float*)d_in[2];
    const float* xs2 = (const float*)d_in[3];
    const float* w0  = (const float*)d_in[4];
    const float* w1  = (const float*)d_in[5];
    const float* w2  = (const float*)d_in[6];
    const float* w3  = (const float*)d_in[7];
    const float* bn0 = (const float*)d_in[8];
    const float* bn1 = (const float*)d_in[9];
    const float* bn2 = (const float*)d_in[10];
    const float* bn3 = (const float*)d_in[11];
    float* out = (float*)d_out;

    // ---- workspace layout ----
    char* p = (char*)d_ws;
    _Float16* xf   = (_Float16*)p; p += (size_t)124 * 1024 * 64 * 2;    // 16.25 MB
    _Float16* gA   = (_Float16*)p; p += (size_t)124 * 4096 * 64 * 2;    // 65 MB (gates L1/L2)
    _Float16* hA   = (_Float16*)p; p += (size_t)124 * 4096 * 32 * 2;    // 32.5 MB (h1+xs2)
    _Float16* hA2  = (_Float16*)p; p += (size_t)124 * 4096 * 32 * 2;    // 32.5 MB (h2+xs1)
    _Float16* hB   = (_Float16*)p; p += (size_t)124 * 16384 * 16 * 2;   // 65 MB   (h3+xs0)
    _Float16* xs0f = (_Float16*)p; p += (size_t)124 * 16384 * 16 * 2;   // 65 MB
    _Float16* wq0u = (_Float16*)p; p += (size_t)4 * 24 * 64 * 32 * 2;   // 384 KB
    _Float16* wq1  = (_Float16*)p; p += (size_t)27 * 64 * 32 * 2;       // 110 KB
    _Float16* wq2u = (_Float16*)p; p += (size_t)4 * 12 * 1024 * 2;      // 96 KB
    _Float16* wq3  = (_Float16*)p; p += (size_t)14 * 1024 * 2;          // 28 KB
    float* sh0 = (float*)p; p += 64 * 4;
    float* sh1 = (float*)p; p += 64 * 4;
    float* sh2 = (float*)p; p += 64 * 4;
    float* sh3 = (float*)p; p += 64 * 4;

    // ---- prep ----
    xconv<<<(4 * 31 * 1024 * 8 + 255) / 256, 256, 0, stream>>>(x, xf);
    xst<16, 16384><<<dim3(64, BB * DD), 256, 0, stream>>>(xs0, xs0f);
    wprep_upA<<<(4 * 24 * 32 * 64 + 255) / 256, 256, 0, stream>>>(w0, bn0, wq0u, 64, 64);
    wprepA<<<(27 * 32 * 64 + 255) / 256, 256, 0, stream>>>(w1, bn1, wq1, 32, 64, 27, 1);
    wprep_upB<<<(4 * 12 * 1024 + 255) / 256, 256, 0, stream>>>(w2, bn2, wq2u, 32, 32, 12);
    wprepC<<<(14 * 1024 + 255) / 256, 256, 0, stream>>>(w3, bn3, wq3, 16, 32, 14, 1);
    bnprep<<<1, 64, 0, stream>>>(bn0, 64, sh0);
    bnprep<<<1, 64, 0, stream>>>(bn1, 64, sh1);
    bnprep<<<1, 64, 0, stream>>>(bn2, 32, sh2);
    bnprep<<<1, 64, 0, stream>>>(bn3, 32, sh3);

    // ---- layer 1 (UNFUSED): up(x) -> conv w0 (64->64) @64; fwd scan; hA = h1+xs2 ----
    conv_up<64, 64, 64, 3><<<dim3(2, 8, BB * DD), 256, 0, stream>>>(xf, wq0u, sh0, gA);
    qscan<32, 4096><<<(BB * 4096 * 4 + 255) / 256, 256, 0, stream>>>(gA, xs2, hA, 0);

    // ---- layer 2 (UNFUSED): deconv w1 (32->64) @64; rev scan; hA2 = h2+xs1 ----
    conv_mfma<32, 64, 64, 27><<<dim3(4, 4, BB * DD), 256, 0, stream>>>(hA, wq1, sh1, gA);
    qscan<32, 4096><<<(BB * 4096 * 4 + 255) / 256, 256, 0, stream>>>(gA, xs1, hA2, 1);

    // ---- layer 3 (FUSED, single-parity): up -> conv w2 (32->32) @128, fwd scan; hB = h3+xs0f ----
    fconv_up1<32, 128, 16, 12, 0, 0><<<dim3(4, 16, BB * 4), 256, 0, stream>>>(
        hA2, wq2u, sh2, xs0f, hB, nullptr);

    // ---- layer 4 (FUSED): deconv w3 (16->32) @128, rev scan; out fp32 NCDHW ----
    fconv3<16, 128, 16, 14, 2, 1><<<dim3(8, 16, BB), 256, 0, stream>>>(
        hB, wq3, sh3, out);
}